// Round 8
// baseline (642.457 us; speedup 1.0000x reference)
//
#include <hip/hip_runtime.h>

#define NNODES 100000
#define NEDGES 1600000
#define NGRAPH 512
#define EPSBN 1e-5f
#define DEGCAP 64   // max in-degree; Binomial(1.6M,1e-5) tail beyond 64 is ~1e-20

typedef unsigned short ushort_t;
typedef unsigned int uint_t;

typedef __attribute__((ext_vector_type(8))) __bf16 bf16x8;
typedef __attribute__((ext_vector_type(4))) float f32x4;

__device__ __forceinline__ float b2f(ushort_t u){ return __uint_as_float(((uint_t)u)<<16); }
__device__ __forceinline__ ushort_t f2b(float f){
  uint_t x = __float_as_uint(f);
  uint_t r = (x + 0x7fffu + ((x>>16)&1u))>>16;
  return (ushort_t)r;
}
__device__ __forceinline__ float lo16(uint_t d){ return b2f((ushort_t)(d & 0xffffu)); }
__device__ __forceinline__ float hi16(uint_t d){ return b2f((ushort_t)(d >> 16)); }

__device__ __forceinline__ f32x4 mfma_bf16(bf16x8 a, bf16x8 b, f32x4 c){
  return __builtin_amdgcn_mfma_f32_16x16x32_bf16(a, b, c, 0, 0, 0);
}

union Frag8 { ushort_t u[8]; bf16x8 v; };

__device__ __forceinline__ bf16x8 cvt8_f32_bf16(const float* __restrict__ p){
  Frag8 f;
  #pragma unroll
  for (int i = 0; i < 8; ++i) f.u[i] = f2b(p[i]);
  return f.v;
}

#define BUILD_BLOCKS ((NEDGES/8 + 255)/256)        // 782
#define GEMM_BLOCKS  ((NNODES + 63)/64)            // 1563

// ---------------- fused: ELL build + gstart + GEMM0 (un-normalized hs0) ----------------
// Build is pinned at the scattered-atomic ceiling (~12 G atomics/s, flat across R4/R5/R6);
// GEMM0 blocks fill the idle issue slots. GEMM0 transposes W0 into LDS itself.
__global__ __launch_bounds__(256) void k_pre(const int* __restrict__ src,
                                             const int* __restrict__ dst,
                                             int* __restrict__ cnt,
                                             int* __restrict__ colx,
                                             const int* __restrict__ batch,
                                             int* __restrict__ gstart,
                                             const float* __restrict__ x,
                                             const float* __restrict__ W0,
                                             ushort_t* __restrict__ hs){
  __shared__ __attribute__((aligned(16))) ushort_t sWT[128*136];

  if (blockIdx.x < BUILD_BLOCKS){
    int e0 = (blockIdx.x*256 + threadIdx.x) * 8;
    if (e0 + 8 <= NEDGES){
      int4 sa = *(const int4*)(src + e0);
      int4 sb = *(const int4*)(src + e0 + 4);
      int4 da = *(const int4*)(dst + e0);
      int4 db = *(const int4*)(dst + e0 + 4);
      int d[8] = {da.x, da.y, da.z, da.w, db.x, db.y, db.z, db.w};
      int s[8] = {sa.x, sa.y, sa.z, sa.w, sb.x, sb.y, sb.z, sb.w};
      int slot[8];
      #pragma unroll
      for (int k = 0; k < 8; ++k) slot[k] = atomicAdd(&cnt[d[k]], 1);
      #pragma unroll
      for (int k = 0; k < 8; ++k) colx[d[k]*DEGCAP + slot[k]] = s[k];
    } else {
      for (int e = e0; e < NEDGES; ++e){
        int dd = dst[e];
        int slot = atomicAdd(&cnt[dd], 1);
        colx[dd*DEGCAP + slot] = src[e];
      }
    }
    return;
  }
  if (blockIdx.x == BUILD_BLOCKS){
    #pragma unroll
    for (int r = 0; r < 2; ++r){
      int g = threadIdx.x + r*256;
      int lo = 0, hi = NNODES;
      while (lo < hi){
        int mid = (lo + hi) >> 1;
        if (batch[mid] < g) lo = mid + 1; else hi = mid;
      }
      gstart[g] = lo;
    }
    if (threadIdx.x == 0) gstart[NGRAPH] = NNODES;
    return;
  }

  // ---- GEMM layer 0: hs[m][n] = bf16( sum_k x[m][k]*W0[k][n] ), un-normalized ----
  int bb = blockIdx.x - BUILD_BLOCKS - 1;
  for (int idx = threadIdx.x; idx < 128*128; idx += 256){
    int c = idx >> 7, jj = idx & 127;
    sWT[jj*136 + c] = f2b(W0[idx]);       // transpose fp32 W0 -> bf16 sWT
  }
  __syncthreads();

  int wave = threadIdx.x >> 6;
  int lane = threadIdx.x & 63;
  int quad = lane >> 4;
  int l16  = lane & 15;
  int row0 = bb*64 + wave*16;

  int m  = row0 + l16;
  int mc = (m < NNODES) ? m : (NNODES - 1);

  const float* ap = x + (size_t)mc*128 + quad*8;
  bf16x8 af0 = cvt8_f32_bf16(ap);
  bf16x8 af1 = cvt8_f32_bf16(ap + 32);
  bf16x8 af2 = cvt8_f32_bf16(ap + 64);
  bf16x8 af3 = cvt8_f32_bf16(ap + 96);

  f32x4 acc[8];
  #pragma unroll
  for (int ct = 0; ct < 8; ++ct){
    const ushort_t* bp = sWT + (ct*16 + l16)*136 + quad*8;
    bf16x8 b0 = *(const bf16x8*)(const void*)(bp);
    bf16x8 b1 = *(const bf16x8*)(const void*)(bp + 32);
    bf16x8 b2 = *(const bf16x8*)(const void*)(bp + 64);
    bf16x8 b3 = *(const bf16x8*)(const void*)(bp + 96);
    f32x4 a_ = {0.f, 0.f, 0.f, 0.f};
    a_ = mfma_bf16(af0, b0, a_);
    a_ = mfma_bf16(af1, b1, a_);
    a_ = mfma_bf16(af2, b2, a_);
    a_ = mfma_bf16(af3, b3, a_);
    acc[ct] = a_;
  }

  int rbase = row0 + quad*4;
  #pragma unroll
  for (int ct = 0; ct < 8; ++ct){
    int colc = ct*16 + l16;
    #pragma unroll
    for (int rg = 0; rg < 4; ++rg){
      int rr = rbase + rg;
      if (rr < NNODES) hs[(size_t)rr*128 + colc] = f2b(acc[ct][rg]);
    }
  }
}

// normalize hs0 rows by rsqrt(deg+1) — cnt is final after k_pre
__global__ void k_norm(ushort_t* __restrict__ hs, const int* __restrict__ cnt){
  int v = blockIdx.x*4 + (threadIdx.x >> 6);
  int lane = threadIdx.x & 63;
  if (v < NNODES){
    float dv = rsqrtf((float)(cnt[v] + 1));
    uint_t* p = (uint_t*)hs + (uint_t)v*64u + lane;
    uint_t d = *p;
    *p = (uint_t)f2b(lo16(d)*dv) | ((uint_t)f2b(hi16(d)*dv) << 16);
  }
}

// ---------------- per-layer kernels ----------------

// GEMM layers 1,2: hs[m][n] = bf16( ( sum_k A[m][k]*WT[n][k] + K[n] ) * rsqrt(cnt[m]+1) )
__global__ __launch_bounds__(256) void k_gemm(const ushort_t* __restrict__ A,
                                              const ushort_t* __restrict__ WT,
                                              const float* __restrict__ Kv,
                                              const int* __restrict__ cnt,
                                              ushort_t* __restrict__ hs){
  __shared__ __attribute__((aligned(16))) ushort_t sWT[128*136];
  {
    const uint4* sp = (const uint4*)WT;
    uint4* dp = (uint4*)sWT;
    for (int i = threadIdx.x; i < (128*136*2)/16; i += 256) dp[i] = sp[i];
  }
  __syncthreads();

  int wave = threadIdx.x >> 6;
  int lane = threadIdx.x & 63;
  int quad = lane >> 4;
  int l16  = lane & 15;
  int row0 = blockIdx.x*64 + wave*16;

  int m  = row0 + l16;
  int mc = (m < NNODES) ? m : (NNODES - 1);

  const ushort_t* ap = A + (size_t)mc*128 + quad*8;
  bf16x8 af0 = *(const bf16x8*)(const void*)(ap);
  bf16x8 af1 = *(const bf16x8*)(const void*)(ap + 32);
  bf16x8 af2 = *(const bf16x8*)(const void*)(ap + 64);
  bf16x8 af3 = *(const bf16x8*)(const void*)(ap + 96);

  f32x4 acc[8];
  #pragma unroll
  for (int ct = 0; ct < 8; ++ct){
    const ushort_t* bp = sWT + (ct*16 + l16)*136 + quad*8;
    bf16x8 b0 = *(const bf16x8*)(const void*)(bp);
    bf16x8 b1 = *(const bf16x8*)(const void*)(bp + 32);
    bf16x8 b2 = *(const bf16x8*)(const void*)(bp + 64);
    bf16x8 b3 = *(const bf16x8*)(const void*)(bp + 96);
    f32x4 a_ = {0.f, 0.f, 0.f, 0.f};
    a_ = mfma_bf16(af0, b0, a_);
    a_ = mfma_bf16(af1, b1, a_);
    a_ = mfma_bf16(af2, b2, a_);
    a_ = mfma_bf16(af3, b3, a_);
    acc[ct] = a_;
  }

  int rbase = row0 + quad*4;
  float dv[4];
  #pragma unroll
  for (int rg = 0; rg < 4; ++rg){
    int rr = rbase + rg;
    int cc = cnt[(rr < NNODES) ? rr : (NNODES - 1)];
    dv[rg] = rsqrtf((float)(cc + 1));
  }
  #pragma unroll
  for (int ct = 0; ct < 8; ++ct){
    int colc = ct*16 + l16;
    float kv = Kv[colc];
    #pragma unroll
    for (int rg = 0; rg < 4; ++rg){
      int rr = rbase + rg;
      if (rr < NNODES){
        float val = (acc[ct][rg] + kv) * dv[rg];
        hs[(size_t)rr*128 + colc] = f2b(val);
      }
    }
  }
}

// Aggregation: wave-per-row, double-buffered 8-bursts (burst r+1 issued before burst r is
// accumulated -> 8..16 gathers in flight, no serial remainder: final burst lane-masked,
// invalid lanes read the hot self row and are cndmask'd to zero).
#define AGG_BLOCKS 2048
#define AGG_WAVES (AGG_BLOCKS*4)
#define AGG_CHUNK ((NNODES + AGG_WAVES - 1) / AGG_WAVES)

template<bool WR>
__global__ __launch_bounds__(256, 8) void k_agg(const ushort_t* __restrict__ hs,
                                                const int* __restrict__ cnt,
                                                const int* __restrict__ colx,
                                                const float* __restrict__ bias,
                                                const int* __restrict__ batch,
                                                ushort_t* __restrict__ rout,
                                                float* __restrict__ poolS,
                                                float* __restrict__ chansum,
                                                float* __restrict__ chansumsq){
  __shared__ float bsum[128];
  __shared__ float bsq[128];
  if (threadIdx.x < 128){ bsum[threadIdx.x] = 0.f; bsq[threadIdx.x] = 0.f; }
  __syncthreads();

  int wave = __builtin_amdgcn_readfirstlane((blockIdx.x << 2) + (threadIdx.x >> 6));
  int lane = threadIdx.x & 63;
  int n0 = wave * AGG_CHUNK;
  int n1 = (n0 + AGG_CHUNK < NNODES) ? (n0 + AGG_CHUNK) : NNODES;

  const uint_t* H = (const uint_t*)hs;
  uint_t* R = (uint_t*)rout;

  float bb0 = bias[lane*2];
  float bb1 = bias[lane*2 + 1];

  float ss0 = 0.f, ss1 = 0.f, sq0 = 0.f, sq1 = 0.f;
  float p0 = 0.f, p1 = 0.f;
  int curg = -1;

  for (int v = n0; v < n1; ++v){
    int g = batch[v];
    if (g != curg){
      if (curg >= 0){
        atomicAdd(&poolS[curg*128 + lane*2],     p0);
        atomicAdd(&poolS[curg*128 + lane*2 + 1], p1);
      }
      p0 = 0.f; p1 = 0.f; curg = g;
    }
    int cv = cnt[v];
    int crow = (lane < cv) ? colx[(uint_t)v*DEGCAP + lane] : v;  // pad lanes -> self (hot)
    uint_t dself = H[(uint_t)v*64u + lane];
    float a0 = lo16(dself), a1 = hi16(dself);

    uint_t d0[8], d1[8];
    int cvp = (cv + 7) & ~7;
    if (cvp){
      #pragma unroll
      for (int k = 0; k < 8; ++k){
        int u = __shfl(crow, k, 64);
        d0[k] = H[(uint_t)u*64u + lane];
      }
      int j = 8;
      for (;;){
        if (j >= cvp){
          // masked final accumulate of d0 (burst base j-8)
          int base = j - 8;
          #pragma unroll
          for (int k = 0; k < 8; ++k){
            bool valmask = (base + k) < cv;
            a0 += valmask ? lo16(d0[k]) : 0.f;
            a1 += valmask ? hi16(d0[k]) : 0.f;
          }
          break;
        }
        #pragma unroll
        for (int k = 0; k < 8; ++k){
          int u = __shfl(crow, (j + k) & 63, 64);
          d1[k] = H[(uint_t)u*64u + lane];
        }
        #pragma unroll
        for (int k = 0; k < 8; ++k){ a0 += lo16(d0[k]); a1 += hi16(d0[k]); }
        j += 8;
        if (j >= cvp){
          int base = j - 8;
          #pragma unroll
          for (int k = 0; k < 8; ++k){
            bool valmask = (base + k) < cv;
            a0 += valmask ? lo16(d1[k]) : 0.f;
            a1 += valmask ? hi16(d1[k]) : 0.f;
          }
          break;
        }
        #pragma unroll
        for (int k = 0; k < 8; ++k){
          int u = __shfl(crow, (j + k) & 63, 64);
          d0[k] = H[(uint_t)u*64u + lane];
        }
        #pragma unroll
        for (int k = 0; k < 8; ++k){ a0 += lo16(d1[k]); a1 += hi16(d1[k]); }
        j += 8;
      }
    }

    float dvv = rsqrtf((float)(cv + 1));
    a0 = fmaxf(a0*dvv + bb0, 0.f);
    a1 = fmaxf(a1*dvv + bb1, 0.f);
    if constexpr (WR)
      R[(uint_t)v*64u + lane] = (uint_t)f2b(a0) | ((uint_t)f2b(a1) << 16);
    ss0 += a0; ss1 += a1;
    sq0 += a0*a0; sq1 += a1*a1;
    p0 += a0; p1 += a1;
  }
  if (curg >= 0){
    atomicAdd(&poolS[curg*128 + lane*2],     p0);
    atomicAdd(&poolS[curg*128 + lane*2 + 1], p1);
  }
  atomicAdd(&bsum[lane*2],     ss0);
  atomicAdd(&bsum[lane*2 + 1], ss1);
  atomicAdd(&bsq[lane*2],      sq0);
  atomicAdd(&bsq[lane*2 + 1],  sq1);
  __syncthreads();
  if (threadIdx.x < 128){
    atomicAdd(&chansum[threadIdx.x],   bsum[threadIdx.x]);
    atomicAdd(&chansumsq[threadIdx.x], bsq[threadIdx.x]);
  }
}

__global__ void k_fold(const float* __restrict__ Wn,
                       const float* __restrict__ chansum, const float* __restrict__ chansumsq,
                       const float* __restrict__ gamma, const float* __restrict__ beta,
                       ushort_t* __restrict__ WT, float* __restrict__ Kv,
                       float* __restrict__ avec, float* __restrict__ cvec){
  __shared__ float red[128];
  int j = blockIdx.x, c = threadIdx.x;
  const float invN = 1.0f / (float)NNODES;
  float mu  = chansum[c] * invN;
  float var = chansumsq[c] * invN - mu*mu;
  float a = gamma[c] * rsqrtf(var + EPSBN);
  float cc = beta[c] - mu*a;
  if (j == 0){ avec[c] = a; cvec[c] = cc; }
  float wv = Wn[c*128 + j];
  WT[j*136 + c] = f2b(a * wv);
  red[c] = cc * wv;
  __syncthreads();
  for (int off = 64; off > 0; off >>= 1){
    if (c < off) red[c] += red[c + off];
    __syncthreads();
  }
  if (c == 0) Kv[j] = red[0];
}

// out[g][i*128+c] = a_i[c]*S_i[g][c] + n_g*c_i[c]; layer-2 BN coeffs computed inline
__global__ void k_final(const float* __restrict__ poolS, const int* __restrict__ gstart,
                        const float* __restrict__ avec, const float* __restrict__ cvec,
                        const float* __restrict__ chansum2, const float* __restrict__ chansumsq2,
                        const float* __restrict__ gamma2, const float* __restrict__ beta2,
                        float* __restrict__ out){
  int g = blockIdx.x, c = threadIdx.x;
  float n = (float)(gstart[g + 1] - gstart[g]);
  #pragma unroll
  for (int i = 0; i < 2; ++i){
    float v = avec[i*128 + c] * poolS[((size_t)i*NGRAPH + g)*128 + c] + n * cvec[i*128 + c];
    out[(size_t)g*384 + i*128 + c] = v;
  }
  const float invN = 1.0f / (float)NNODES;
  float mu  = chansum2[c] * invN;
  float var = chansumsq2[c] * invN - mu*mu;
  float a2 = gamma2[c] * rsqrtf(var + EPSBN);
  float c2 = beta2[c] - mu*a2;
  float v2 = a2 * poolS[((size_t)2*NGRAPH + g)*128 + c] + n * c2;
  out[(size_t)g*384 + 2*128 + c] = v2;
}

extern "C" void kernel_launch(void* const* d_in, const int* in_sizes, int n_in,
                              void* d_out, int out_size, void* d_ws, size_t ws_size,
                              hipStream_t stream){
  (void)in_sizes; (void)n_in; (void)out_size; (void)ws_size;

  const float* x     = (const float*)d_in[0];
  const int*   ei    = (const int*)d_in[1];
  const int*   batch = (const int*)d_in[2];
  const float* Wp[3] = {(const float*)d_in[3], (const float*)d_in[7],  (const float*)d_in[11]};
  const float* bp[3] = {(const float*)d_in[4], (const float*)d_in[8],  (const float*)d_in[12]};
  const float* gp[3] = {(const float*)d_in[5], (const float*)d_in[9],  (const float*)d_in[13]};
  const float* tp[3] = {(const float*)d_in[6], (const float*)d_in[10], (const float*)d_in[14]};
  const int* srcp = ei;
  const int* dstp = ei + NEDGES;

  char* w = (char*)d_ws;
  size_t off = 0;
  auto take = [&](size_t bytes) -> char* {
    char* p = w + off;
    off += (bytes + 511) & ~(size_t)511;
    return p;
  };
  int*      cnt       = (int*)take((size_t)NNODES*4);
  int*      colx      = (int*)take((size_t)NNODES*DEGCAP*4);
  int*      gstart    = (int*)take((NGRAPH+1)*4);
  ushort_t* hs        = (ushort_t*)take((size_t)NNODES*128*2);
  ushort_t* rbuf      = (ushort_t*)take((size_t)NNODES*128*2);
  ushort_t* WT        = (ushort_t*)take(128*136*2);
  float*    Kv        = (float*)take(128*4);
  float*    chanstats = (float*)take(3*256*4);
  float*    poolS     = (float*)take((size_t)3*NGRAPH*128*4);
  float*    avec      = (float*)take(2*128*4);
  float*    cvec      = (float*)take(2*128*4);

  hipMemsetAsync(cnt,       0, (size_t)NNODES*4,       stream);
  hipMemsetAsync(poolS,     0, (size_t)3*NGRAPH*128*4, stream);
  hipMemsetAsync(chanstats, 0, 3*256*4,                stream);

  // fused: ELL build + gstart + GEMM0 (un-normalized hs0)
  k_pre<<<BUILD_BLOCKS + 1 + GEMM_BLOCKS, 256, 0, stream>>>(
      srcp, dstp, cnt, colx, batch, gstart, x, Wp[0], hs);
  k_norm<<<(NNODES + 3)/4, 256, 0, stream>>>(hs, cnt);

  // layer 0
  k_agg<true><<<AGG_BLOCKS, 256, 0, stream>>>(hs, cnt, colx, bp[0], batch, rbuf,
                                              poolS, chanstats, chanstats + 128);
  k_fold<<<128, 128, 0, stream>>>(Wp[1], chanstats, chanstats + 128,
                                  gp[0], tp[0], WT, Kv, avec, cvec);
  // layer 1
  k_gemm<<<GEMM_BLOCKS, 256, 0, stream>>>(rbuf, WT, Kv, cnt, hs);
  k_agg<true><<<AGG_BLOCKS, 256, 0, stream>>>(hs, cnt, colx, bp[1], batch, rbuf,
                                              poolS + (size_t)NGRAPH*128,
                                              chanstats + 256, chanstats + 256 + 128);
  k_fold<<<128, 128, 0, stream>>>(Wp[2], chanstats + 256, chanstats + 256 + 128,
                                  gp[1], tp[1], WT, Kv, avec + 128, cvec + 128);
  // layer 2
  k_gemm<<<GEMM_BLOCKS, 256, 0, stream>>>(rbuf, WT, Kv, cnt, hs);
  k_agg<false><<<AGG_BLOCKS, 256, 0, stream>>>(hs, cnt, colx, bp[2], batch, rbuf,
                                               poolS + (size_t)2*NGRAPH*128,
                                               chanstats + 512, chanstats + 512 + 128);

  k_final<<<NGRAPH, 128, 0, stream>>>(poolS, gstart, avec, cvec,
                                      chanstats + 512, chanstats + 512 + 128,
                                      gp[2], tp[2], (float*)d_out);
}

// Round 10
// 576.935 us; speedup vs baseline: 1.1136x; 1.1136x over previous
//
#include <hip/hip_runtime.h>

#define NNODES 100000
#define NEDGES 1600000
#define NGRAPH 512
#define EPSBN 1e-5f
#define DEGCAP 64    // max in-degree; Binomial tail beyond 64 ~1e-20
#define NBUCK 256    // dst buckets of 512 nodes (196 used)
#define BSH 9
#define BCAP 9216    // per-bucket capacity: mean 8163, 11.7 sigma margin
#define P1_BLOCKS ((NEDGES + 4095)/4096)   // 391
#define GEMM_BLOCKS ((NNODES + 63)/64)     // 1563

typedef unsigned short ushort_t;
typedef unsigned int uint_t;

typedef __attribute__((ext_vector_type(8))) __bf16 bf16x8;
typedef __attribute__((ext_vector_type(4))) float f32x4;

__device__ __forceinline__ float b2f(ushort_t u){ return __uint_as_float(((uint_t)u)<<16); }
__device__ __forceinline__ ushort_t f2b(float f){
  uint_t x = __float_as_uint(f);
  uint_t r = (x + 0x7fffu + ((x>>16)&1u))>>16;
  return (ushort_t)r;
}
__device__ __forceinline__ float lo16(uint_t d){ return b2f((ushort_t)(d & 0xffffu)); }
__device__ __forceinline__ float hi16(uint_t d){ return b2f((ushort_t)(d >> 16)); }

__device__ __forceinline__ f32x4 mfma_bf16(bf16x8 a, bf16x8 b, f32x4 c){
  return __builtin_amdgcn_mfma_f32_16x16x32_bf16(a, b, c, 0, 0, 0);
}

union Frag8 { ushort_t u[8]; bf16x8 v; };

__device__ __forceinline__ bf16x8 cvt8_f32_bf16(const float* __restrict__ p){
  Frag8 f;
  #pragma unroll
  for (int i = 0; i < 8; ++i) f.u[i] = f2b(p[i]);
  return f.v;
}

// ---- phase 1 (fused): edge bucketing + gstart + GEMM0 (raw bf16 hs0) ----
__global__ __launch_bounds__(256) void k_p1(const int* __restrict__ src,
                                            const int* __restrict__ dst,
                                            int* __restrict__ gBucket,   // stride 16 ints
                                            int2* __restrict__ ebuf,
                                            const int* __restrict__ batch,
                                            int* __restrict__ gstart,
                                            const float* __restrict__ x,
                                            const float* __restrict__ W0,
                                            ushort_t* __restrict__ hs){
  __shared__ __attribute__((aligned(16))) ushort_t sMem[128*136];

  if (blockIdx.x < P1_BLOCKS){
    int* cntL  = (int*)sMem;
    int* baseL = cntL + NBUCK;
    int* ofsL  = baseL + NBUCK;
    int t = threadIdx.x;
    if (t < NBUCK){ cntL[t] = 0; ofsL[t] = 0; }
    __syncthreads();

    int base = blockIdx.x * 4096;
    int e0 = base + t*16;
    int s[16], d[16];
    int ne = 0;
    if (e0 + 16 <= NEDGES){
      #pragma unroll
      for (int q = 0; q < 4; ++q){
        int4 sv = *(const int4*)(src + e0 + q*4);
        int4 dv = *(const int4*)(dst + e0 + q*4);
        s[q*4+0]=sv.x; s[q*4+1]=sv.y; s[q*4+2]=sv.z; s[q*4+3]=sv.w;
        d[q*4+0]=dv.x; d[q*4+1]=dv.y; d[q*4+2]=dv.z; d[q*4+3]=dv.w;
      }
      ne = 16;
    } else {
      for (int e = e0; e < NEDGES && ne < 16; ++e, ++ne){
        s[ne] = src[e]; d[ne] = dst[e];
      }
    }
    for (int k = 0; k < ne; ++k) atomicAdd(&cntL[d[k] >> BSH], 1);
    __syncthreads();
    if (t < NBUCK){
      int c = cntL[t];
      baseL[t] = c ? atomicAdd(&gBucket[t*16], c) : 0;
    }
    __syncthreads();
    for (int k = 0; k < ne; ++k){
      int b = d[k] >> BSH;
      int o = atomicAdd(&ofsL[b], 1);
      ebuf[(size_t)b*BCAP + baseL[b] + o] = make_int2(s[k], d[k]);
    }
    return;
  }
  if (blockIdx.x == P1_BLOCKS){
    #pragma unroll
    for (int r = 0; r < 2; ++r){
      int g = threadIdx.x + r*256;
      int lo = 0, hi = NNODES;
      while (lo < hi){
        int mid = (lo + hi) >> 1;
        if (batch[mid] < g) lo = mid + 1; else hi = mid;
      }
      gstart[g] = lo;
    }
    if (threadIdx.x == 0) gstart[NGRAPH] = NNODES;
    return;
  }

  // ---- GEMM layer 0: hs[m][n] = bf16( sum_k x[m][k]*W0[k][n] ), un-normalized ----
  ushort_t* sWT = sMem;
  int bb = blockIdx.x - P1_BLOCKS - 1;
  for (int idx = threadIdx.x; idx < 128*128; idx += 256){
    int c = idx >> 7, jj = idx & 127;
    sWT[jj*136 + c] = f2b(W0[idx]);
  }
  __syncthreads();

  int wave = threadIdx.x >> 6;
  int lane = threadIdx.x & 63;
  int quad = lane >> 4;
  int l16  = lane & 15;
  int row0 = bb*64 + wave*16;

  int m  = row0 + l16;
  int mc = (m < NNODES) ? m : (NNODES - 1);

  const float* ap = x + (size_t)mc*128 + quad*8;
  bf16x8 af0 = cvt8_f32_bf16(ap);
  bf16x8 af1 = cvt8_f32_bf16(ap + 32);
  bf16x8 af2 = cvt8_f32_bf16(ap + 64);
  bf16x8 af3 = cvt8_f32_bf16(ap + 96);

  f32x4 acc[8];
  #pragma unroll
  for (int ct = 0; ct < 8; ++ct){
    const ushort_t* bp = sWT + (ct*16 + l16)*136 + quad*8;
    bf16x8 b0 = *(const bf16x8*)(const void*)(bp);
    bf16x8 b1 = *(const bf16x8*)(const void*)(bp + 32);
    bf16x8 b2 = *(const bf16x8*)(const void*)(bp + 64);
    bf16x8 b3 = *(const bf16x8*)(const void*)(bp + 96);
    f32x4 a_ = {0.f, 0.f, 0.f, 0.f};
    a_ = mfma_bf16(af0, b0, a_);
    a_ = mfma_bf16(af1, b1, a_);
    a_ = mfma_bf16(af2, b2, a_);
    a_ = mfma_bf16(af3, b3, a_);
    acc[ct] = a_;
  }

  int rbase = row0 + quad*4;
  #pragma unroll
  for (int ct = 0; ct < 8; ++ct){
    int colc = ct*16 + l16;
    #pragma unroll
    for (int rg = 0; rg < 4; ++rg){
      int rr = rbase + rg;
      if (rr < NNODES) hs[(size_t)rr*128 + colc] = f2b(acc[ct][rg]);
    }
  }
}

// ---- phase 2: per-bucket placement into colx + cnt + in-place hs normalization ----
__global__ __launch_bounds__(256) void k_p2(const int2* __restrict__ ebuf,
                                            const int* __restrict__ gBucket,
                                            int* __restrict__ colx,
                                            int* __restrict__ cnt,
                                            ushort_t* __restrict__ hs){
  __shared__ int slotcnt[512];
  int t = threadIdx.x;
  int b = blockIdx.x;
  slotcnt[t] = 0; slotcnt[t + 256] = 0;
  __syncthreads();

  int nb = gBucket[b*16];
  int vbase = b << BSH;

  for (int e = t; e < nb; e += 256){
    int2 p = ebuf[(size_t)b*BCAP + e];
    int slot = atomicAdd(&slotcnt[p.y - vbase], 1);
    colx[p.y*DEGCAP + slot] = p.x;
  }
  __syncthreads();

  #pragma unroll
  for (int r = 0; r < 2; ++r){
    int i = t + r*256;
    int v = vbase + i;
    if (v < NNODES) cnt[v] = slotcnt[i];
  }

  uint_t* H = (uint_t*)hs;
  for (int idx = t; idx < 512*64; idx += 256){
    int r = idx >> 6;
    int v = vbase + r;
    if (v < NNODES){
      int lane = idx & 63;
      float dv = rsqrtf((float)(slotcnt[r] + 1));
      uint_t d = H[(uint_t)v*64u + lane];
      H[(uint_t)v*64u + lane] = (uint_t)f2b(lo16(d)*dv) | ((uint_t)f2b(hi16(d)*dv) << 16);
    }
  }
}

// ---- GEMM layers 1,2: hs[m][n] = bf16( (sum_k A[m][k]*WT[n][k] + K[n]) * rsqrt(cnt[m]+1) ) ----
__global__ __launch_bounds__(256) void k_gemm(const ushort_t* __restrict__ A,
                                              const ushort_t* __restrict__ WT,
                                              const float* __restrict__ Kv,
                                              const int* __restrict__ cnt,
                                              ushort_t* __restrict__ hs){
  __shared__ __attribute__((aligned(16))) ushort_t sWT[128*136];
  {
    const uint4* sp = (const uint4*)WT;
    uint4* dp = (uint4*)sWT;
    for (int i = threadIdx.x; i < (128*136*2)/16; i += 256) dp[i] = sp[i];
  }
  __syncthreads();

  int wave = threadIdx.x >> 6;
  int lane = threadIdx.x & 63;
  int quad = lane >> 4;
  int l16  = lane & 15;
  int row0 = blockIdx.x*64 + wave*16;

  int m  = row0 + l16;
  int mc = (m < NNODES) ? m : (NNODES - 1);

  const ushort_t* ap = A + (size_t)mc*128 + quad*8;
  bf16x8 af0 = *(const bf16x8*)(const void*)(ap);
  bf16x8 af1 = *(const bf16x8*)(const void*)(ap + 32);
  bf16x8 af2 = *(const bf16x8*)(const void*)(ap + 64);
  bf16x8 af3 = *(const bf16x8*)(const void*)(ap + 96);

  f32x4 acc[8];
  #pragma unroll
  for (int ct = 0; ct < 8; ++ct){
    const ushort_t* bp = sWT + (ct*16 + l16)*136 + quad*8;
    bf16x8 b0 = *(const bf16x8*)(const void*)(bp);
    bf16x8 b1 = *(const bf16x8*)(const void*)(bp + 32);
    bf16x8 b2 = *(const bf16x8*)(const void*)(bp + 64);
    bf16x8 b3 = *(const bf16x8*)(const void*)(bp + 96);
    f32x4 a_ = {0.f, 0.f, 0.f, 0.f};
    a_ = mfma_bf16(af0, b0, a_);
    a_ = mfma_bf16(af1, b1, a_);
    a_ = mfma_bf16(af2, b2, a_);
    a_ = mfma_bf16(af3, b3, a_);
    acc[ct] = a_;
  }

  int rbase = row0 + quad*4;
  float dv[4];
  #pragma unroll
  for (int rg = 0; rg < 4; ++rg){
    int rr = rbase + rg;
    int cc = cnt[(rr < NNODES) ? rr : (NNODES - 1)];
    dv[rg] = rsqrtf((float)(cc + 1));
  }
  #pragma unroll
  for (int ct = 0; ct < 8; ++ct){
    int colc = ct*16 + l16;
    float kv = Kv[colc];
    #pragma unroll
    for (int rg = 0; rg < 4; ++rg){
      int rr = rbase + rg;
      if (rr < NNODES){
        float val = (acc[ct][rg] + kv) * dv[rg];
        hs[(size_t)rr*128 + colc] = f2b(val);
      }
    }
  }
}

// ---- aggregation: wave-per-row, bf16 gathers, 8 independent in flight ----
#define AGG_BLOCKS 2048
#define AGG_WAVES (AGG_BLOCKS*4)
#define AGG_CHUNK ((NNODES + AGG_WAVES - 1) / AGG_WAVES)

template<bool WR>
__global__ __launch_bounds__(256, 8) void k_agg(const ushort_t* __restrict__ hs,
                                                const int* __restrict__ cnt,
                                                const int* __restrict__ colx,
                                                const float* __restrict__ bias,
                                                const int* __restrict__ batch,
                                                ushort_t* __restrict__ rout,
                                                float* __restrict__ poolS,
                                                float* __restrict__ chansum,
                                                float* __restrict__ chansumsq){
  __shared__ float bsum[128];
  __shared__ float bsq[128];
  if (threadIdx.x < 128){ bsum[threadIdx.x] = 0.f; bsq[threadIdx.x] = 0.f; }
  __syncthreads();

  int wave = __builtin_amdgcn_readfirstlane((blockIdx.x << 2) + (threadIdx.x >> 6));
  int lane = threadIdx.x & 63;
  int n0 = wave * AGG_CHUNK;
  int n1 = (n0 + AGG_CHUNK < NNODES) ? (n0 + AGG_CHUNK) : NNODES;

  const uint_t* H = (const uint_t*)hs;
  uint_t* R = (uint_t*)rout;

  float bb0 = bias[lane*2];
  float bb1 = bias[lane*2 + 1];

  float ss0 = 0.f, ss1 = 0.f, sq0 = 0.f, sq1 = 0.f;
  float p0 = 0.f, p1 = 0.f;
  int curg = -1;

  for (int v = n0; v < n1; ++v){
    int g = batch[v];
    if (g != curg){
      if (curg >= 0){
        atomicAdd(&poolS[curg*128 + lane*2],     p0);
        atomicAdd(&poolS[curg*128 + lane*2 + 1], p1);
      }
      p0 = 0.f; p1 = 0.f; curg = g;
    }
    int cv = cnt[v];
    int crow = (lane < cv) ? colx[(uint_t)v*DEGCAP + lane] : v;   // masked: skip pad sectors
    uint_t dself = H[(uint_t)v*64u + lane];
    float a0 = lo16(dself), a1 = hi16(dself);

    int j = 0;
    for (; j + 7 < cv; j += 8){
      int u0 = __shfl(crow, j+0, 64);
      int u1 = __shfl(crow, j+1, 64);
      int u2 = __shfl(crow, j+2, 64);
      int u3 = __shfl(crow, j+3, 64);
      int u4 = __shfl(crow, j+4, 64);
      int u5 = __shfl(crow, j+5, 64);
      int u6 = __shfl(crow, j+6, 64);
      int u7 = __shfl(crow, j+7, 64);
      uint_t d0 = H[(uint_t)u0*64u + lane];
      uint_t d1 = H[(uint_t)u1*64u + lane];
      uint_t d2 = H[(uint_t)u2*64u + lane];
      uint_t d3 = H[(uint_t)u3*64u + lane];
      uint_t d4 = H[(uint_t)u4*64u + lane];
      uint_t d5 = H[(uint_t)u5*64u + lane];
      uint_t d6 = H[(uint_t)u6*64u + lane];
      uint_t d7 = H[(uint_t)u7*64u + lane];
      a0 += lo16(d0) + lo16(d1) + lo16(d2) + lo16(d3)
          + lo16(d4) + lo16(d5) + lo16(d6) + lo16(d7);
      a1 += hi16(d0) + hi16(d1) + hi16(d2) + hi16(d3)
          + hi16(d4) + hi16(d5) + hi16(d6) + hi16(d7);
    }
    for (; j < cv; ++j){
      int u = __shfl(crow, j, 64);
      uint_t d = H[(uint_t)u*64u + lane];
      a0 += lo16(d);
      a1 += hi16(d);
    }

    float dvv = rsqrtf((float)(cv + 1));
    a0 = fmaxf(a0*dvv + bb0, 0.f);
    a1 = fmaxf(a1*dvv + bb1, 0.f);
    if constexpr (WR)
      R[(uint_t)v*64u + lane] = (uint_t)f2b(a0) | ((uint_t)f2b(a1) << 16);
    ss0 += a0; ss1 += a1;
    sq0 += a0*a0; sq1 += a1*a1;
    p0 += a0; p1 += a1;
  }
  if (curg >= 0){
    atomicAdd(&poolS[curg*128 + lane*2],     p0);
    atomicAdd(&poolS[curg*128 + lane*2 + 1], p1);
  }
  atomicAdd(&bsum[lane*2],     ss0);
  atomicAdd(&bsum[lane*2 + 1], ss1);
  atomicAdd(&bsq[lane*2],      sq0);
  atomicAdd(&bsq[lane*2 + 1],  sq1);
  __syncthreads();
  if (threadIdx.x < 128){
    atomicAdd(&chansum[threadIdx.x],   bsum[threadIdx.x]);
    atomicAdd(&chansumsq[threadIdx.x], bsq[threadIdx.x]);
  }
}

__global__ void k_fold(const float* __restrict__ Wn,
                       const float* __restrict__ chansum, const float* __restrict__ chansumsq,
                       const float* __restrict__ gamma, const float* __restrict__ beta,
                       ushort_t* __restrict__ WT, float* __restrict__ Kv,
                       float* __restrict__ avec, float* __restrict__ cvec){
  __shared__ float red[128];
  int j = blockIdx.x, c = threadIdx.x;
  const float invN = 1.0f / (float)NNODES;
  float mu  = chansum[c] * invN;
  float var = chansumsq[c] * invN - mu*mu;
  float a = gamma[c] * rsqrtf(var + EPSBN);
  float cc = beta[c] - mu*a;
  if (j == 0){ avec[c] = a; cvec[c] = cc; }
  float wv = Wn[c*128 + j];
  WT[j*136 + c] = f2b(a * wv);
  red[c] = cc * wv;
  __syncthreads();
  for (int off = 64; off > 0; off >>= 1){
    if (c < off) red[c] += red[c + off];
    __syncthreads();
  }
  if (c == 0) Kv[j] = red[0];
}

__global__ void k_final(const float* __restrict__ poolS, const int* __restrict__ gstart,
                        const float* __restrict__ avec, const float* __restrict__ cvec,
                        const float* __restrict__ chansum2, const float* __restrict__ chansumsq2,
                        const float* __restrict__ gamma2, const float* __restrict__ beta2,
                        float* __restrict__ out){
  int g = blockIdx.x, c = threadIdx.x;
  float n = (float)(gstart[g + 1] - gstart[g]);
  #pragma unroll
  for (int i = 0; i < 2; ++i){
    float v = avec[i*128 + c] * poolS[((size_t)i*NGRAPH + g)*128 + c] + n * cvec[i*128 + c];
    out[(size_t)g*384 + i*128 + c] = v;
  }
  const float invN = 1.0f / (float)NNODES;
  float mu  = chansum2[c] * invN;
  float var = chansumsq2[c] * invN - mu*mu;
  float a2 = gamma2[c] * rsqrtf(var + EPSBN);
  float c2 = beta2[c] - mu*a2;
  float v2 = a2 * poolS[((size_t)2*NGRAPH + g)*128 + c] + n * c2;
  out[(size_t)g*384 + 2*128 + c] = v2;
}

extern "C" void kernel_launch(void* const* d_in, const int* in_sizes, int n_in,
                              void* d_out, int out_size, void* d_ws, size_t ws_size,
                              hipStream_t stream){
  (void)in_sizes; (void)n_in; (void)out_size; (void)ws_size;

  const float* x     = (const float*)d_in[0];
  const int*   ei    = (const int*)d_in[1];
  const int*   batch = (const int*)d_in[2];
  const float* Wp[3] = {(const float*)d_in[3], (const float*)d_in[7],  (const float*)d_in[11]};
  const float* bp[3] = {(const float*)d_in[4], (const float*)d_in[8],  (const float*)d_in[12]};
  const float* gp[3] = {(const float*)d_in[5], (const float*)d_in[9],  (const float*)d_in[13]};
  const float* tp[3] = {(const float*)d_in[6], (const float*)d_in[10], (const float*)d_in[14]};
  const int* srcp = ei;
  const int* dstp = ei + NEDGES;

  char* w = (char*)d_ws;
  size_t off = 0;
  auto take = [&](size_t bytes) -> char* {
    char* p = w + off;
    off += (bytes + 511) & ~(size_t)511;
    return p;
  };
  int*      cnt       = (int*)take((size_t)NNODES*4);
  int*      colx      = (int*)take((size_t)NNODES*DEGCAP*4);
  int*      gstart    = (int*)take((NGRAPH+1)*4);
  ushort_t* hs        = (ushort_t*)take((size_t)NNODES*128*2);
  ushort_t* rbuf      = (ushort_t*)take((size_t)NNODES*128*2);   // also aliased as ebuf pre-agg0
  ushort_t* WT        = (ushort_t*)take(128*136*2);
  float*    Kv        = (float*)take(128*4);
  float*    chanstats = (float*)take(3*256*4);
  float*    poolS     = (float*)take((size_t)3*NGRAPH*128*4);
  float*    avec      = (float*)take(2*128*4);
  float*    cvec      = (float*)take(2*128*4);
  int*      gBucket   = (int*)take(NBUCK*16*4);

  // ebuf aliases rbuf: ebuf consumed by k_p2 before agg0 first writes rbuf.
  int2* ebuf = (int2*)rbuf;   // needs NBUCK*BCAP*8 = 18.9 MB <= 25.6 MB

  hipMemsetAsync(gBucket,   0, NBUCK*16*4,             stream);
  hipMemsetAsync(poolS,     0, (size_t)3*NGRAPH*128*4, stream);
  hipMemsetAsync(chanstats, 0, 3*256*4,                stream);

  // phase 1: bucket edges + gstart + GEMM0 (raw hs0)
  k_p1<<<P1_BLOCKS + 1 + GEMM_BLOCKS, 256, 0, stream>>>(
      srcp, dstp, gBucket, ebuf, batch, gstart, x, Wp[0], hs);
  // phase 2: place colx, write cnt, normalize hs0 in place
  k_p2<<<NBUCK, 256, 0, stream>>>(ebuf, gBucket, colx, cnt, hs);

  // layer 0
  k_agg<true><<<AGG_BLOCKS, 256, 0, stream>>>(hs, cnt, colx, bp[0], batch, rbuf,
                                              poolS, chanstats, chanstats + 128);
  k_fold<<<128, 128, 0, stream>>>(Wp[1], chanstats, chanstats + 128,
                                  gp[0], tp[0], WT, Kv, avec, cvec);
  // layer 1
  k_gemm<<<GEMM_BLOCKS, 256, 0, stream>>>(rbuf, WT, Kv, cnt, hs);
  k_agg<true><<<AGG_BLOCKS, 256, 0, stream>>>(hs, cnt, colx, bp[1], batch, rbuf,
                                              poolS + (size_t)NGRAPH*128,
                                              chanstats + 256, chanstats + 256 + 128);
  k_fold<<<128, 128, 0, stream>>>(Wp[2], chanstats + 256, chanstats + 256 + 128,
                                  gp[1], tp[1], WT, Kv, avec + 128, cvec + 128);
  // layer 2
  k_gemm<<<GEMM_BLOCKS, 256, 0, stream>>>(rbuf, WT, Kv, cnt, hs);
  k_agg<false><<<AGG_BLOCKS, 256, 0, stream>>>(hs, cnt, colx, bp[2], batch, rbuf,
                                               poolS + (size_t)2*NGRAPH*128,
                                               chanstats + 512, chanstats + 512 + 128);

  k_final<<<NGRAPH, 128, 0, stream>>>(poolS, gstart, avec, cvec,
                                      chanstats + 512, chanstats + 512 + 128,
                                      gp[2], tp[2], (float*)d_out);
}